// Round 6
// baseline (249.463 us; speedup 1.0000x reference)
//
#include <hip/hip_runtime.h>
#include <hip/hip_bf16.h>
#include <math.h>

#define TT 1024
#define HH 2048
#define EE 32
#define II 1024
#define BK 64
#define SA 72     // LDS row stride in bf16 elems (64 + 8 pad -> 2-way bank alias only)
#define TS (128 * SA)
#define KSP 32    // router split-K chunks (K-chunk = 64)
#define MB 64     // router tokens per block

typedef __attribute__((ext_vector_type(8))) short bf16x8;
typedef __attribute__((ext_vector_type(8))) unsigned short ushort8;
typedef __attribute__((ext_vector_type(4))) float f32x4;

__device__ __forceinline__ unsigned short f2b(float f) {
    union { float f; unsigned u; } c; c.f = f;
    unsigned r = c.u + 0x7FFFu + ((c.u >> 16) & 1u);   // RNE to bf16
    return (unsigned short)(r >> 16);
}
__device__ __forceinline__ float b2f(unsigned short u) {
    union { unsigned u; float f; } c; c.u = ((unsigned)u) << 16;
    return c.f;
}
__device__ __forceinline__ unsigned cvtpk(float lo, float hi) {
    unsigned r;
    asm("v_cvt_pk_bf16_f32 %0, %1, %2" : "=v"(r) : "v"(lo), "v"(hi));
    return r;
}
__device__ __forceinline__ ushort8 pack8(float4 a, float4 b) {
    union { unsigned u[4]; ushort8 s; } cv;
    cv.u[0] = cvtpk(a.x, a.y); cv.u[1] = cvtpk(a.z, a.w);
    cv.u[2] = cvtpk(b.x, b.y); cv.u[3] = cvtpk(b.z, b.w);
    return cv.s;
}

// ---------------- router mix: split-K tiled fp32 GEMM ----------------
__global__ __launch_bounds__(256) void k_mix(const float* __restrict__ x,
                                             const float* __restrict__ wqkv,
                                             float* __restrict__ mixp) {
    __shared__ float xs[MB][68];
    __shared__ float ws_[96][68];
    const int tm0 = blockIdx.x * MB;
    const int k0 = blockIdx.y * 64;
    const int tid = threadIdx.x;
#pragma unroll
    for (int q = 0; q < 4; ++q) {
        int p = tid + q * 256;
        int row = p >> 4, c4 = (p & 15) * 4;
        *(float4*)&xs[row][c4] = *(const float4*)(x + (size_t)(tm0 + row) * HH + k0 + c4);
    }
#pragma unroll
    for (int q = 0; q < 6; ++q) {
        int p = tid + q * 256;
        int row = p >> 4, c4 = (p & 15) * 4;
        *(float4*)&ws_[row][c4] = *(const float4*)(wqkv + (size_t)row * HH + k0 + c4);
    }
    __syncthreads();
    const int tg = tid >> 4, cg = tid & 15;
    float acc[4][6];
#pragma unroll
    for (int i = 0; i < 4; ++i)
#pragma unroll
        for (int c = 0; c < 6; ++c) acc[i][c] = 0.f;
    for (int k = 0; k < 64; k += 4) {
        float4 xv[4], wv[6];
#pragma unroll
        for (int i = 0; i < 4; ++i) xv[i] = *(const float4*)&xs[tg * 4 + i][k];
#pragma unroll
        for (int c = 0; c < 6; ++c) wv[c] = *(const float4*)&ws_[cg * 6 + c][k];
#pragma unroll
        for (int i = 0; i < 4; ++i)
#pragma unroll
            for (int c = 0; c < 6; ++c)
                acc[i][c] += xv[i].x * wv[c].x + xv[i].y * wv[c].y +
                             xv[i].z * wv[c].z + xv[i].w * wv[c].w;
    }
    float* dst = mixp + ((size_t)blockIdx.y * TT + tm0) * 96;
#pragma unroll
    for (int i = 0; i < 4; ++i)
#pragma unroll
        for (int c = 0; c < 6; ++c)
            dst[(tg * 4 + i) * 96 + cg * 6 + c] = acc[i][c];
}

// ---------------- router: reduce partials + attention + top-2 + scatter ----------------
__global__ void k_router_attn(const float* __restrict__ mixp,
                              int* __restrict__ cnt,
                              int* __restrict__ tok_list,
                              float* __restrict__ wgt_list) {
    const int t = blockIdx.x;
    __shared__ float mrow[96];
    __shared__ float lg[EE];
    const int tid = threadIdx.x;
    if (tid < 96) {
        float s = 0.f;
        for (int sp = 0; sp < KSP; ++sp)          // fixed order -> deterministic
            s += mixp[((size_t)sp * TT + t) * 96 + tid];
        mrow[tid] = s;
    }
    __syncthreads();
    if (tid < EE) {
        float q = mrow[tid];
        float m = -1e30f;
        for (int f = 0; f < EE; ++f) m = fmaxf(m, q * mrow[32 + f]);
        float s = 0.f, a = 0.f;
        for (int f = 0; f < EE; ++f) {
            float ex = expf(q * mrow[32 + f] - m);
            s += ex;
            a += ex * mrow[64 + f];
        }
        lg[tid] = a / s;
    }
    __syncthreads();
    if (tid == 0) {
        int b0 = 0; float v0 = lg[0];
        for (int e2 = 1; e2 < EE; ++e2)
            if (lg[e2] > v0) { v0 = lg[e2]; b0 = e2; }
        int b1 = -1; float v1 = -1e30f;
        for (int e2 = 0; e2 < EE; ++e2)
            if (e2 != b0 && lg[e2] > v1) { v1 = lg[e2]; b1 = e2; }
        float ex = expf(v1 - v0);
        float w0 = 1.f / (1.f + ex);
        float w1 = ex / (1.f + ex);
        int p0 = atomicAdd(&cnt[b0], 1);
        tok_list[b0 * TT + p0] = t * 2 + 0;
        wgt_list[b0 * TT + p0] = w0;
        int p1 = atomicAdd(&cnt[b1], 1);
        tok_list[b1 * TT + p1] = t * 2 + 1;
        wgt_list[b1 * TT + p1] = w1;
    }
}

// ---------------- gemm1: gu = x[tok] @ w1[e]^T  (bf16 MFMA, LDS-dbuf, 1 barrier/K-step) ----------------
__global__ __launch_bounds__(256, 2) void k_gemm1(
    const float* __restrict__ x, const float* __restrict__ w1,
    const int* __restrict__ cnt, const int* __restrict__ tok_list,
    unsigned short* __restrict__ gu) {
    const int e = blockIdx.y;
    const int M = cnt[e];
    const int m0 = blockIdx.z * 128;
    if (m0 >= M) return;
    const int n0 = blockIdx.x * 128;

    __shared__ __align__(16) unsigned short As[2 * TS];
    __shared__ __align__(16) unsigned short Bs[2 * TS];
    __shared__ int ts[128];

    const int tid = threadIdx.x;
    if (tid < 128) {
        int mr = m0 + tid;
        ts[tid] = (mr < M) ? tok_list[e * TT + mr] : -1;
    }
    __syncthreads();

    const float* w1e = w1 + (size_t)e * (2 * II) * HH;
    const int wid = tid >> 6;
    const int lane = tid & 63;
    const int wm = wid >> 1, wn = wid & 1;
    const int fr = lane & 15;
    const int kg = lane >> 4;
    const int srow = tid >> 3;
    const int sc8 = (tid & 7) * 8;

    f32x4 acc[4][4];
#pragma unroll
    for (int i = 0; i < 4; ++i)
#pragma unroll
        for (int j = 0; j < 4; ++j) acc[i][j] = (f32x4){0.f, 0.f, 0.f, 0.f};

    float4 pa[8], pb[8];
    const float4 f4z = {0.f, 0.f, 0.f, 0.f};

#define G1_LOAD(kk)                                                              \
    do {                                                                         \
        const int kkv_ = (kk);                                                   \
        _Pragma("unroll")                                                        \
        for (int q = 0; q < 4; ++q) {                                            \
            int row = srow + q * 32;                                             \
            int entry = ts[row];                                                 \
            if (entry >= 0) {                                                    \
                const float* gpa_ = x + (size_t)(entry >> 1) * HH + kkv_ + sc8;  \
                pa[2 * q] = ((const float4*)gpa_)[0];                            \
                pa[2 * q + 1] = ((const float4*)gpa_)[1];                        \
            } else { pa[2 * q] = f4z; pa[2 * q + 1] = f4z; }                     \
            const float* gpb_ = w1e + (size_t)(n0 + row) * HH + kkv_ + sc8;      \
            pb[2 * q] = ((const float4*)gpb_)[0];                                \
            pb[2 * q + 1] = ((const float4*)gpb_)[1];                            \
        }                                                                        \
    } while (0)

#define G1_CVT(buf)                                                              \
    do {                                                                         \
        unsigned short* Ad = As + (buf)*TS;                                      \
        unsigned short* Bd = Bs + (buf)*TS;                                      \
        _Pragma("unroll")                                                        \
        for (int q = 0; q < 4; ++q) {                                            \
            int row = srow + q * 32;                                             \
            *(ushort8*)&Ad[row * SA + sc8] = pack8(pa[2 * q], pa[2 * q + 1]);    \
            *(ushort8*)&Bd[row * SA + sc8] = pack8(pb[2 * q], pb[2 * q + 1]);    \
        }                                                                        \
    } while (0)

    const int NS = HH / BK;   // 32
    G1_LOAD(0);
    G1_CVT(0);
    G1_LOAD(BK);
    __syncthreads();

    for (int s = 0; s < NS; ++s) {
        const int cur = s & 1;
        if (s + 1 < NS) {
            G1_CVT(cur ^ 1);                         // cvt tile s+1 -> other buffer
            if (s + 2 < NS) G1_LOAD((s + 2) * BK);   // issue loads tile s+2
        }
        const unsigned short* Ar = As + cur * TS;
        const unsigned short* Br = Bs + cur * TS;
#pragma unroll
        for (int kh = 0; kh < 2; ++kh) {
            const int kb = kh * 32 + kg * 8;
            bf16x8 a[4], b[4];
#pragma unroll
            for (int i = 0; i < 4; ++i)
                a[i] = *(const bf16x8*)&Ar[(wm * 64 + i * 16 + fr) * SA + kb];
#pragma unroll
            for (int j = 0; j < 4; ++j)
                b[j] = *(const bf16x8*)&Br[(wn * 64 + j * 16 + fr) * SA + kb];
#pragma unroll
            for (int i = 0; i < 4; ++i)
#pragma unroll
                for (int j = 0; j < 4; ++j)
                    acc[i][j] = __builtin_amdgcn_mfma_f32_16x16x32_bf16(a[i], b[j], acc[i][j], 0, 0, 0);
        }
        __syncthreads();
    }
#undef G1_LOAD
#undef G1_CVT

#pragma unroll
    for (int mi = 0; mi < 4; ++mi) {
#pragma unroll
        for (int reg = 0; reg < 4; ++reg) {
            int m = wm * 64 + mi * 16 + kg * 4 + reg;
            int entry = ts[m];
            if (entry < 0) continue;
            unsigned short* dst = gu + (size_t)entry * (2 * II) + n0 + wn * 64;
#pragma unroll
            for (int ni = 0; ni < 4; ++ni)
                dst[ni * 16 + fr] = f2b(acc[mi][ni][reg]);
        }
    }
}

// ---------------- gemm2: po[entry] = (silu(gate)*up*w) @ w2[e]^T  (bf16 MFMA, LDS-dbuf) ----------------
__global__ __launch_bounds__(256, 2) void k_gemm2(
    const unsigned short* __restrict__ gu, const float* __restrict__ w2,
    const int* __restrict__ cnt, const int* __restrict__ tok_list,
    const float* __restrict__ wgt_list, float* __restrict__ po) {
    const int e = blockIdx.y;
    const int M = cnt[e];
    const int m0 = blockIdx.z * 128;
    if (m0 >= M) return;
    const int n0 = blockIdx.x * 128;

    __shared__ __align__(16) unsigned short As[2 * TS];
    __shared__ __align__(16) unsigned short Bs[2 * TS];
    __shared__ int ts[128];
    __shared__ float tw[128];

    const int tid = threadIdx.x;
    if (tid < 128) {
        int mr = m0 + tid;
        if (mr < M) {
            ts[tid] = tok_list[e * TT + mr];
            tw[tid] = wgt_list[e * TT + mr];
        } else { ts[tid] = -1; tw[tid] = 0.f; }
    }
    __syncthreads();

    const float* w2e = w2 + (size_t)e * HH * II;
    const int wid = tid >> 6;
    const int lane = tid & 63;
    const int wm = wid >> 1, wn = wid & 1;
    const int fr = lane & 15;
    const int kg = lane >> 4;
    const int srow = tid >> 3;
    const int sc8 = (tid & 7) * 8;

    f32x4 acc[4][4];
#pragma unroll
    for (int i = 0; i < 4; ++i)
#pragma unroll
        for (int j = 0; j < 4; ++j) acc[i][j] = (f32x4){0.f, 0.f, 0.f, 0.f};

    ushort8 pg[4], pu[4];
    float4 pb[8];
    const ushort8 u8z = {0, 0, 0, 0, 0, 0, 0, 0};

#define G2_LOAD(kk)                                                                  \
    do {                                                                             \
        const int kkv_ = (kk);                                                       \
        _Pragma("unroll")                                                            \
        for (int q = 0; q < 4; ++q) {                                                \
            int row = srow + q * 32;                                                 \
            int entry = ts[row];                                                     \
            if (entry >= 0) {                                                        \
                pg[q] = *(const ushort8*)(gu + (size_t)entry * (2 * II) + kkv_ + sc8);      \
                pu[q] = *(const ushort8*)(gu + (size_t)entry * (2 * II) + II + kkv_ + sc8); \
            } else { pg[q] = u8z; pu[q] = u8z; }                                     \
            const float* gpb_ = w2e + (size_t)(n0 + row) * II + kkv_ + sc8;          \
            pb[2 * q] = ((const float4*)gpb_)[0];                                    \
            pb[2 * q + 1] = ((const float4*)gpb_)[1];                                \
        }                                                                            \
    } while (0)

#define G2_CVT(buf)                                                                  \
    do {                                                                             \
        unsigned short* Ad = As + (buf)*TS;                                          \
        unsigned short* Bd = Bs + (buf)*TS;                                          \
        _Pragma("unroll")                                                            \
        for (int q = 0; q < 4; ++q) {                                                \
            int row = srow + q * 32;                                                 \
            float w = tw[row];                                                       \
            float s0[8];                                                             \
            _Pragma("unroll")                                                        \
            for (int j = 0; j < 8; ++j) {                                            \
                float g = b2f((unsigned short)pg[q][j]);                             \
                float u = b2f((unsigned short)pu[q][j]);                             \
                s0[j] = (g / (1.f + __expf(-g))) * u * w;                            \
            }                                                                        \
            float4 lo = make_float4(s0[0], s0[1], s0[2], s0[3]);                     \
            float4 hi = make_float4(s0[4], s0[5], s0[6], s0[7]);                     \
            *(ushort8*)&Ad[row * SA + sc8] = pack8(lo, hi);                          \
            *(ushort8*)&Bd[row * SA + sc8] = pack8(pb[2 * q], pb[2 * q + 1]);        \
        }                                                                            \
    } while (0)

    const int NS = II / BK;   // 16
    G2_LOAD(0);
    G2_CVT(0);
    G2_LOAD(BK);
    __syncthreads();

    for (int s = 0; s < NS; ++s) {
        const int cur = s & 1;
        if (s + 1 < NS) {
            G2_CVT(cur ^ 1);
            if (s + 2 < NS) G2_LOAD((s + 2) * BK);
        }
        const unsigned short* Ar = As + cur * TS;
        const unsigned short* Br = Bs + cur * TS;
#pragma unroll
        for (int kh = 0; kh < 2; ++kh) {
            const int kb = kh * 32 + kg * 8;
            bf16x8 a[4], b[4];
#pragma unroll
            for (int i = 0; i < 4; ++i)
                a[i] = *(const bf16x8*)&Ar[(wm * 64 + i * 16 + fr) * SA + kb];
#pragma unroll
            for (int j = 0; j < 4; ++j)
                b[j] = *(const bf16x8*)&Br[(wn * 64 + j * 16 + fr) * SA + kb];
#pragma unroll
            for (int i = 0; i < 4; ++i)
#pragma unroll
                for (int j = 0; j < 4; ++j)
                    acc[i][j] = __builtin_amdgcn_mfma_f32_16x16x32_bf16(a[i], b[j], acc[i][j], 0, 0, 0);
        }
        __syncthreads();
    }
#undef G2_LOAD
#undef G2_CVT

#pragma unroll
    for (int mi = 0; mi < 4; ++mi) {
#pragma unroll
        for (int reg = 0; reg < 4; ++reg) {
            int m = wm * 64 + mi * 16 + kg * 4 + reg;
            int entry = ts[m];
            if (entry < 0) continue;
            float* op = po + (size_t)entry * HH + n0 + wn * 64;
#pragma unroll
            for (int ni = 0; ni < 4; ++ni)
                op[ni * 16 + fr] = acc[mi][ni][reg];
        }
    }
}

// ---------------- combine: out[t] = po[2t] + po[2t+1] ----------------
__global__ __launch_bounds__(256) void k_combine(const float* __restrict__ po,
                                                 float* __restrict__ out) {
    int i = blockIdx.x * 256 + threadIdx.x;
    int t = i / (HH / 4);
    int c = i % (HH / 4);
    float4 a = ((const float4*)(po + (size_t)(2 * t) * HH))[c];
    float4 b = ((const float4*)(po + (size_t)(2 * t + 1) * HH))[c];
    float4 r = make_float4(a.x + b.x, a.y + b.y, a.z + b.z, a.w + b.w);
    ((float4*)(out + (size_t)t * HH))[c] = r;
}

extern "C" void kernel_launch(void* const* d_in, const int* in_sizes, int n_in,
                              void* d_out, int out_size, void* d_ws, size_t ws_size,
                              hipStream_t stream) {
    const float* x    = (const float*)d_in[0];
    const float* wqkv = (const float*)d_in[1];
    const float* w1   = (const float*)d_in[2];
    const float* w2   = (const float*)d_in[3];
    float* out = (float*)d_out;

    char* ws = (char*)d_ws;
    float* mixp           = (float*)(ws);                      // 12582912 B
    float* wgt_list       = (float*)(ws + 12582912);           // 131072 B
    int*   tok_list       = (int*)  (ws + 12713984);           // 131072 B
    int*   cnt            = (int*)  (ws + 12845056);           // 128 B
    unsigned short* gu    = (unsigned short*)(ws + 12845184);  // 8388608 B
    float* po             = (float*)(ws + 21233792);           // 16777216 B

    (void)hipMemsetAsync(cnt, 0, 128, stream);

    k_mix<<<dim3(TT / MB, KSP), 256, 0, stream>>>(x, wqkv, mixp);
    k_router_attn<<<TT, 128, 0, stream>>>(mixp, cnt, tok_list, wgt_list);
    k_gemm1<<<dim3(2 * II / 128, EE, 8), 256, 0, stream>>>(x, w1, cnt, tok_list, gu);
    k_gemm2<<<dim3(HH / 128, EE, 8), 256, 0, stream>>>(gu, w2, cnt, tok_list, wgt_list, po);
    k_combine<<<TT * HH / 4 / 256, 256, 0, stream>>>(po, out);
}